// Round 7
// baseline (255.744 us; speedup 1.0000x reference)
//
#include <hip/hip_runtime.h>

// BinaryLSTMCell fused kernel v6 for MI355X (gfx950).
// B=65536, D=256, U=256. out = [h_new | h_new | c_new], f32.
//
// v2-v5b invariant: MfmaUtil pinned at 25%, wall ~228us across occupancy
// 24-39%, all pipelining/stagger/setprio variants -> per-step block barrier
// convoys the 4 waves; stalls add instead of overlap.
// v6: ZERO barriers in K loop. Each wave stages its OWN side's A-strip into a
// wave-private LDS buffer (lane l stages row l&31 - matches the 32x32 MFMA
// A-operand row layout), converts f32->f16 hi/lo itself, reads its own frags.
// Waves fully independent; epilogue keeps the only 2 __syncthreads.

#define NB 65536

typedef _Float16 f16x8 __attribute__((ext_vector_type(8)));
typedef __fp16 fp16x2 __attribute__((ext_vector_type(2)));
typedef float f32x16 __attribute__((ext_vector_type(16)));

__device__ __forceinline__ float htanh(float x) {
  return __builtin_amdgcn_fmed3f(x, -1.0f, 1.0f);
}

// ---------------------------------------------------------------------------
// prep: binarize both weight matrices into 1024 pre-built MFMA B-fragments.
// fragid = ((k16*2 + side)*8 + u32)*4 + gate, 1KB each:
//   lane l holds 16B: n = gate*256 + u32*32 + (l&31), k = k16*16 + (l>>5)*8 + e.
// ---------------------------------------------------------------------------
__global__ void prep_w(const float* __restrict__ Kf, const float* __restrict__ RKf,
                       unsigned short* __restrict__ wfrag) {
  __shared__ unsigned short sgn[32][72];
  const int b = blockIdx.x;            // 256 blocks
  const int side = b >> 7, kt = (b >> 4) & 7, nt = b & 15;
  const float* M = side ? RKf : Kf;
  const int t = threadIdx.x;

  {  // load 32k x 64n tile, coalesced, store signs
    const int k = t >> 3, n8 = (t & 7) << 3;
    const float* p = M + (kt * 32 + k) * 1024 + nt * 64 + n8;
    float4 v0 = *(const float4*)p;
    float4 v1 = *(const float4*)(p + 4);
    float xs[8] = {v0.x, v0.y, v0.z, v0.w, v1.x, v1.y, v1.z, v1.w};
#pragma unroll
    for (int i = 0; i < 8; ++i)
      sgn[k][n8 + i] = (xs[i] >= 0.f) ? 0x3C00u : 0xBC00u;
  }
  __syncthreads();

  const int fl = t >> 6, l = t & 63;
  const int j = fl >> 1, uhh = fl & 1;
  const int nloc = uhh * 32 + (l & 31);
  const int kloc = j * 16 + (l >> 5) * 8;
  unsigned short o[8];
#pragma unroll
  for (int e = 0; e < 8; ++e) o[e] = sgn[kloc + e][nloc];
  const int ng = nt * 64 + nloc;
  const int gate = ng >> 8, u32 = (ng >> 5) & 7;
  const int k16 = kt * 2 + j;
  const int fragid = ((k16 * 2 + side) * 8 + u32) * 4 + gate;
  uint4 ov;
  ov.x = (unsigned)o[0] | ((unsigned)o[1] << 16);
  ov.y = (unsigned)o[2] | ((unsigned)o[3] << 16);
  ov.z = (unsigned)o[4] | ((unsigned)o[5] << 16);
  ov.w = (unsigned)o[6] | ((unsigned)o[7] << 16);
  *(uint4*)((char*)wfrag + fragid * 1024 + l * 16) = ov;
}

// ---------------------------------------------------------------------------
// main: 256 thr (4 waves: sw x wu). Block tile m32 x u64, both sides.
// Each wave: m32 x (4 gates x 32u) of side sw; acc = 4 x f32x16.
// K loop: 8 steps of 32 f32-k, NO BARRIERS: wave-private LDS staging.
// LDS per wave: 2 x 4KB buffers, [chunk8][slot32][16B]; chunk c holds
// kl = ((c>>1)&1)*16 + (c&1)*8 + e (c<4: hi, c>=4: lo at c-4).
// ---------------------------------------------------------------------------
__global__ __launch_bounds__(256, 3)
void blstm_main(const float* __restrict__ xin, const float* __restrict__ hin,
                const float* __restrict__ cin, const unsigned short* __restrict__ wfrag,
                float* __restrict__ out) {
  __shared__ char smem[32768];   // 4 waves x 8KB private; epilogue ex aliases

  const int bid = blockIdx.x;
  const int swz = (bid & 7) * 1024 + (bid >> 3);   // XCD swizzle, 8192 % 8 == 0
  const int m0 = (swz >> 2) << 5;
  const int ub = swz & 3;

  const int tid = threadIdx.x;
  const int lane = tid & 63;
  const int w = tid >> 6;
  const int wu = w & 1, sw = w >> 1;               // side sw (0=x, 1=r)
  const int l31 = lane & 31, lh = lane >> 5;

  // wave-private staging: lane l stages row l31, k-half lh (16 f32 per step)
  char* const myBuf = smem + w * 8192;
  char* const wrB = myBuf + (lh * 2) * 512 + l31 * 16;       // hi chunk 2lh
  const char* const rdB = myBuf + lh * 512 + l31 * 16;       // frag chunk base

  const float* const aP = (sw ? hin : xin) + (m0 + l31) * 256 + lh * 16;

  // W fragment base: byte = (sw*8 + ub*2 + wu)*4096 + lane*16; +k16*65536; +g*1024
  const char* const wqB = (const char*)wfrag + ((sw * 8 + ub * 2 + wu) << 12) + lane * 16;

  f32x16 acc[4] = {};
  float4 a0, a1, a2, a3;

#define ALOAD(S) do {                                                       \
    a0 = *(const float4*)(aP + (S) * 32);                                   \
    a1 = *(const float4*)(aP + (S) * 32 + 4);                               \
    a2 = *(const float4*)(aP + (S) * 32 + 8);                               \
    a3 = *(const float4*)(aP + (S) * 32 + 12);                              \
  } while (0)

#define CW(DST) do {                                                        \
    float v0_ = a0.x, v1_ = a0.y, v2_ = a0.z, v3_ = a0.w;                   \
    float v4_ = a1.x, v5_ = a1.y, v6_ = a1.z, v7_ = a1.w;                   \
    float v8_ = a2.x, v9_ = a2.y, vA_ = a2.z, vB_ = a2.w;                   \
    float vC_ = a3.x, vD_ = a3.y, vE_ = a3.z, vF_ = a3.w;                   \
    if (sw) {                                                               \
      v0_ = htanh(v0_); v1_ = htanh(v1_); v2_ = htanh(v2_); v3_ = htanh(v3_); \
      v4_ = htanh(v4_); v5_ = htanh(v5_); v6_ = htanh(v6_); v7_ = htanh(v7_); \
      v8_ = htanh(v8_); v9_ = htanh(v9_); vA_ = htanh(vA_); vB_ = htanh(vB_); \
      vC_ = htanh(vC_); vD_ = htanh(vD_); vE_ = htanh(vE_); vF_ = htanh(vF_); \
    }                                                                       \
    fp16x2 h01_ = __builtin_amdgcn_cvt_pkrtz(v0_, v1_);                     \
    fp16x2 h23_ = __builtin_amdgcn_cvt_pkrtz(v2_, v3_);                     \
    fp16x2 h45_ = __builtin_amdgcn_cvt_pkrtz(v4_, v5_);                     \
    fp16x2 h67_ = __builtin_amdgcn_cvt_pkrtz(v6_, v7_);                     \
    fp16x2 h89_ = __builtin_amdgcn_cvt_pkrtz(v8_, v9_);                     \
    fp16x2 hAB_ = __builtin_amdgcn_cvt_pkrtz(vA_, vB_);                     \
    fp16x2 hCD_ = __builtin_amdgcn_cvt_pkrtz(vC_, vD_);                     \
    fp16x2 hEF_ = __builtin_amdgcn_cvt_pkrtz(vE_, vF_);                     \
    fp16x2 l01_ = __builtin_amdgcn_cvt_pkrtz(v0_ - (float)h01_[0], v1_ - (float)h01_[1]); \
    fp16x2 l23_ = __builtin_amdgcn_cvt_pkrtz(v2_ - (float)h23_[0], v3_ - (float)h23_[1]); \
    fp16x2 l45_ = __builtin_amdgcn_cvt_pkrtz(v4_ - (float)h45_[0], v5_ - (float)h45_[1]); \
    fp16x2 l67_ = __builtin_amdgcn_cvt_pkrtz(v6_ - (float)h67_[0], v7_ - (float)h67_[1]); \
    fp16x2 l89_ = __builtin_amdgcn_cvt_pkrtz(v8_ - (float)h89_[0], v9_ - (float)h89_[1]); \
    fp16x2 lAB_ = __builtin_amdgcn_cvt_pkrtz(vA_ - (float)hAB_[0], vB_ - (float)hAB_[1]); \
    fp16x2 lCD_ = __builtin_amdgcn_cvt_pkrtz(vC_ - (float)hCD_[0], vD_ - (float)hCD_[1]); \
    fp16x2 lEF_ = __builtin_amdgcn_cvt_pkrtz(vE_ - (float)hEF_[0], vF_ - (float)hEF_[1]); \
    uint4 H0_, H1_, L0_, L1_;                                               \
    H0_.x = __builtin_bit_cast(unsigned, h01_); H0_.y = __builtin_bit_cast(unsigned, h23_); \
    H0_.z = __builtin_bit_cast(unsigned, h45_); H0_.w = __builtin_bit_cast(unsigned, h67_); \
    H1_.x = __builtin_bit_cast(unsigned, h89_); H1_.y = __builtin_bit_cast(unsigned, hAB_); \
    H1_.z = __builtin_bit_cast(unsigned, hCD_); H1_.w = __builtin_bit_cast(unsigned, hEF_); \
    L0_.x = __builtin_bit_cast(unsigned, l01_); L0_.y = __builtin_bit_cast(unsigned, l23_); \
    L0_.z = __builtin_bit_cast(unsigned, l45_); L0_.w = __builtin_bit_cast(unsigned, l67_); \
    L1_.x = __builtin_bit_cast(unsigned, l89_); L1_.y = __builtin_bit_cast(unsigned, lAB_); \
    L1_.z = __builtin_bit_cast(unsigned, lCD_); L1_.w = __builtin_bit_cast(unsigned, lEF_); \
    *(uint4*)(DST) = H0_;                                                   \
    *(uint4*)((DST) + 512) = H1_;                                           \
    *(uint4*)((DST) + 2048) = L0_;                                          \
    *(uint4*)((DST) + 2560) = L1_;                                          \
  } while (0)

#define MFMA4(AF, W0, W1, W2, W3) do {                                      \
    acc[0] = __builtin_amdgcn_mfma_f32_32x32x16_f16(AF, W0, acc[0], 0, 0, 0); \
    acc[1] = __builtin_amdgcn_mfma_f32_32x32x16_f16(AF, W1, acc[1], 0, 0, 0); \
    acc[2] = __builtin_amdgcn_mfma_f32_32x32x16_f16(AF, W2, acc[2], 0, 0, 0); \
    acc[3] = __builtin_amdgcn_mfma_f32_32x32x16_f16(AF, W3, acc[3], 0, 0, 0); \
  } while (0)

  // ---- prologue: stage A(0) into buf0; A(1) into regs. No barriers. ----
  ALOAD(0);
  CW(wrB);
  ALOAD(1);

#pragma unroll
  for (int s = 0; s < 8; ++s) {
    // frags of step s from buf[s&1] (own wave's writes; in-order DS pipe)
    const char* rb = rdB + (s & 1) * 4096;
    f16x8 ah0 = *(const f16x8*)(rb);             // j0 hi  (chunk lh)
    f16x8 ah1 = *(const f16x8*)(rb + 1024);      // j1 hi  (chunk 2+lh)
    f16x8 al0 = *(const f16x8*)(rb + 2048);      // j0 lo  (chunk 4+lh)
    f16x8 al1 = *(const f16x8*)(rb + 3072);      // j1 lo  (chunk 6+lh)

    // W fragments for this step (L2-resident)
    const char* wp0 = wqB + (s * 2) * 65536;
    f16x8 wa0 = *(const f16x8*)(wp0);
    f16x8 wa1 = *(const f16x8*)(wp0 + 1024);
    f16x8 wa2 = *(const f16x8*)(wp0 + 2048);
    f16x8 wa3 = *(const f16x8*)(wp0 + 3072);
    const char* wp1 = wp0 + 65536;
    f16x8 wb0 = *(const f16x8*)(wp1);
    f16x8 wb1 = *(const f16x8*)(wp1 + 1024);
    f16x8 wb2 = *(const f16x8*)(wp1 + 2048);
    f16x8 wb3 = *(const f16x8*)(wp1 + 3072);

    // stage A(s+1) into the other buffer; prefetch A(s+2)
    if (s < 7) CW(wrB + ((s + 1) & 1) * 4096);
    if (s < 6) ALOAD(s + 2);

    __builtin_amdgcn_s_setprio(1);
    MFMA4(ah0, wa0, wa1, wa2, wa3);
    MFMA4(al0, wa0, wa1, wa2, wa3);
    MFMA4(ah1, wb0, wb1, wb2, wb3);
    MFMA4(al1, wb0, wb1, wb2, wb3);
    __builtin_amdgcn_s_setprio(0);
  }
#undef MFMA4
#undef CW
#undef ALOAD

  // ---- epilogue (unchanged from v5b, which passed) ----
  // C/D layout (verified): col = lane&31, row = (reg&3) + 8*(reg>>2) + 4*(lane>>5)
  __syncthreads();   // all waves done with private staging before aliasing
  float* ex = (float*)(smem + wu * 16384);  // [gate4][quad4][64 lanes x 16B]

  if (sw == 1) {     // r-waves dump raw acc quads
#pragma unroll
    for (int g = 0; g < 4; ++g)
#pragma unroll
      for (int q = 0; q < 4; ++q) {
        float4 v;
        v.x = acc[g][q * 4 + 0]; v.y = acc[g][q * 4 + 1];
        v.z = acc[g][q * 4 + 2]; v.w = acc[g][q * 4 + 3];
        *(float4*)((char*)ex + (g * 4 + q) * 1024 + lane * 16) = v;
      }
  }
  __syncthreads();
  if (sw == 0) {     // x-waves combine gates and write out
    const int gu = ub * 64 + wu * 32 + l31;
#pragma unroll
    for (int q = 0; q < 4; ++q) {
      float4 ri = *(const float4*)((const char*)ex + (0 * 4 + q) * 1024 + lane * 16);
      float4 rf = *(const float4*)((const char*)ex + (1 * 4 + q) * 1024 + lane * 16);
      float4 rc = *(const float4*)((const char*)ex + (2 * 4 + q) * 1024 + lane * 16);
      float4 ro = *(const float4*)((const char*)ex + (3 * 4 + q) * 1024 + lane * 16);
#pragma unroll
      for (int t = 0; t < 4; ++t) {
        const int r = q * 4 + t;
        const int row = t + q * 8 + lh * 4;
        const int grow = m0 + row;
        const float xi = htanh(acc[0][r]);
        const float xf = htanh(acc[1][r]);
        const float xc = htanh(acc[2][r]);
        const float xo = htanh(acc[3][r]);
        const float riv = ((const float*)&ri)[t];
        const float rfv = ((const float*)&rf)[t];
        const float rcv = ((const float*)&rc)[t];
        const float rov = ((const float*)&ro)[t];
        // reference gate crossing: f = ht(x_i + r_f), i = ht(x_f + r_i)
        const float fg   = htanh(xi + rfv);
        const float ig   = htanh(xf + riv);
        const float cand = htanh(xc + rcv);
        const float og   = htanh(xo + rov);
        const float ct = htanh(cin[grow * 256 + gu]);
        const float cn = fg * ct + ig * cand;
        const float hn = htanh(og * htanh(cn));
        const int o1 = grow * 256 + gu;
        out[o1] = hn;
        out[NB * 256 + o1] = hn;
        out[2 * NB * 256 + o1] = cn;
      }
    }
  }
}

extern "C" void kernel_launch(void* const* d_in, const int* in_sizes, int n_in,
                              void* d_out, int out_size, void* d_ws, size_t ws_size,
                              hipStream_t stream) {
  const float* xin = (const float*)d_in[0];
  const float* hin = (const float*)d_in[1];
  const float* cin = (const float*)d_in[2];
  const float* kf  = (const float*)d_in[3];
  const float* rkf = (const float*)d_in[4];
  float* out = (float*)d_out;

  unsigned short* wfrag = (unsigned short*)d_ws;    // 1024 frags x 1KB = 1MB

  prep_w<<<256, 256, 0, stream>>>(kf, rkf, wfrag);
  blstm_main<<<8192, 256, 0, stream>>>(xin, hin, cin, wfrag, out);
}